// Round 1
// baseline (296.925 us; speedup 1.0000x reference)
//
#include <hip/hip_runtime.h>
#include <hip/hip_bf16.h>

// AFT-Full fused pipeline, B=8, S=D=1024.
//   qkv = x @ [wq|wk|wv]^T + b        (bf16 MFMA GEMM, M=8192,N=3072,K=1024)
//   E   = exp(k + w)                  (elementwise)
//   vT, EKT = transpose(v), transpose(exp(k))   (per batch)
//   num = E @ v     (BT GEMM vs vT)   den = exp(w) @ exp(k)  (BT GEMM vs EKT)
//   y   = sigmoid(q) * num / den
//   out = y @ out_w^T + out_b         (fp32 store)

typedef float  f32x4  __attribute__((ext_vector_type(4)));
typedef short  short8 __attribute__((ext_vector_type(8)));
typedef __bf16 bf16x8 __attribute__((ext_vector_type(8)));

__device__ __forceinline__ ushort f2bf(float f){
  uint u = __builtin_bit_cast(uint, f);
  u += 0x7fffu + ((u >> 16) & 1u);          // RNE
  return (ushort)(u >> 16);
}
__device__ __forceinline__ float bf2f(ushort u){
  uint v = ((uint)u) << 16;
  return __builtin_bit_cast(float, v);
}

__device__ __forceinline__ void gload16(const ushort* g, ushort* l){
  __builtin_amdgcn_global_load_lds(
      (const __attribute__((address_space(1))) void*)g,
      (__attribute__((address_space(3))) void*)l, 16, 0, 0);
}

__device__ __forceinline__ f32x4 mfma16(short8 a, short8 b, f32x4 c){
  return __builtin_amdgcn_mfma_f32_16x16x32_bf16(
      __builtin_bit_cast(bf16x8, a), __builtin_bit_cast(bf16x8, b), c, 0, 0, 0);
}

// ---------------------------------------------------------------------------
// BT GEMM: C[M,N] = A[M,K] @ B[N,K]^T (+bias[n]).  A,B bf16 (ushort bits),
// acc fp32.  128x128 tile, 4 waves (2x2), BK=64, global_load_lds width 16
// with source-side XOR pre-swizzle; ds_read_b128 with matching XOR on read.
// EPI=0: bf16 store; EPI=1: fp32 store. Batched via grid.z (strides in elems).
// ---------------------------------------------------------------------------
template<int EPI>
__global__ __launch_bounds__(256) void gemm_bt(
    const ushort* __restrict__ A, const ushort* __restrict__ B,
    void* __restrict__ C, const float* __restrict__ bias,
    int N, int K, long sA, long sB, long sC)
{
  __shared__ ushort As[128 * 64] __attribute__((aligned(16)));
  __shared__ ushort Bs[128 * 64] __attribute__((aligned(16)));

  const int tid  = threadIdx.x;
  const int lane = tid & 63;
  const int wid  = tid >> 6;
  const int wm   = wid >> 1;           // 0..1
  const int wn   = wid & 1;            // 0..1
  const long z   = blockIdx.z;
  const long tileM = (long)blockIdx.y * 128;
  const long tileN = (long)blockIdx.x * 128;

  const ushort* Ab = A + z * sA + tileM * K;
  const ushort* Bb = B + z * sB + tileN * K;

  // staging: 4 slots/thread per tile; chunk = 16B = 8 bf16.
  long gOff[4]; int lOff[4];
#pragma unroll
  for (int j = 0; j < 4; ++j) {
    int chunk = j * 256 + tid;         // wave-contiguous: j*256 + wid*64 + lane
    int row   = chunk >> 3;            // 0..127
    int c16   = (chunk & 7) ^ (row & 7);   // pre-swizzled source column chunk
    gOff[j]   = (long)row * K + c16 * 8;
    lOff[j]   = chunk * 8;
  }

  f32x4 acc[4][4];
#pragma unroll
  for (int i = 0; i < 4; ++i)
#pragma unroll
    for (int j = 0; j < 4; ++j) acc[i][j] = (f32x4)0.f;

  const int rA0 = wm * 64 + (lane & 15);
  const int rB0 = wn * 64 + (lane & 15);
  const int cw0 = lane >> 4;           // 0..3 (8-elem chunk within 32-K slice)

  for (int kt = 0; kt < K; kt += 64) {
    __syncthreads();                   // previous tile's ds_reads complete
#pragma unroll
    for (int j = 0; j < 4; ++j) {
      gload16(Ab + gOff[j] + kt, &As[lOff[j]]);
      gload16(Bb + gOff[j] + kt, &Bs[lOff[j]]);
    }
    __syncthreads();                   // compiler emits vmcnt(0) before barrier

    short8 af[4][2], bf[4][2];
#pragma unroll
    for (int f = 0; f < 4; ++f) {
      int ra = rA0 + f * 16;
      int rb = rB0 + f * 16;
#pragma unroll
      for (int kk = 0; kk < 2; ++kk) {
        af[f][kk] = *(const short8*)&As[ra * 64 + (((kk * 4 + cw0) ^ (ra & 7)) * 8)];
        bf[f][kk] = *(const short8*)&Bs[rb * 64 + (((kk * 4 + cw0) ^ (rb & 7)) * 8)];
      }
    }
#pragma unroll
    for (int kk = 0; kk < 2; ++kk)
#pragma unroll
      for (int fi = 0; fi < 4; ++fi)
#pragma unroll
        for (int fj = 0; fj < 4; ++fj)
          acc[fi][fj] = mfma16(af[fi][kk], bf[fj][kk], acc[fi][fj]);
  }

  // epilogue: lane l, reg r -> C[row=(l>>4)*4+r][col=l&15] within 16x16 frag
#pragma unroll
  for (int fi = 0; fi < 4; ++fi) {
    long gm0 = tileM + wm * 64 + fi * 16 + (lane >> 4) * 4;
#pragma unroll
    for (int fj = 0; fj < 4; ++fj) {
      long gn = tileN + wn * 64 + fj * 16 + (lane & 15);
      float bv = bias ? bias[gn] : 0.f;
      if (EPI == 0) {
        ushort* Cp = (ushort*)C + z * sC;
#pragma unroll
        for (int r = 0; r < 4; ++r)
          Cp[(gm0 + r) * (long)N + gn] = f2bf(acc[fi][fj][r] + bv);
      } else {
        float* Cp = (float*)C + z * sC;
#pragma unroll
        for (int r = 0; r < 4; ++r)
          Cp[(gm0 + r) * (long)N + gn] = acc[fi][fj][r] + bv;
      }
    }
  }
}

// ---------------------------------------------------------------------------
// elementwise / prep kernels
// ---------------------------------------------------------------------------
__global__ void cvt_x(const float* __restrict__ in, ushort* __restrict__ out){
  long i4 = ((long)blockIdx.x * 256 + threadIdx.x) * 4;
  float4 v = *(const float4*)&in[i4];
  ushort4 o;
  o.x = f2bf(v.x); o.y = f2bf(v.y); o.z = f2bf(v.z); o.w = f2bf(v.w);
  *(ushort4*)&out[i4] = o;
}

// wq|wk|wv -> wcat bf16 [3072][1024]; out_w -> owb; exp(w) -> ewb; biases -> bcat
__global__ void prep(const float* __restrict__ wq, const float* __restrict__ wk,
                     const float* __restrict__ wv, const float* __restrict__ ow,
                     const float* __restrict__ w,
                     const float* __restrict__ bq, const float* __restrict__ bk,
                     const float* __restrict__ bv,
                     ushort* __restrict__ wcat, ushort* __restrict__ owb,
                     ushort* __restrict__ ewb, float* __restrict__ bcat)
{
  long i4 = ((long)blockIdx.x * 256 + threadIdx.x) * 4;
  const long MB = 1048576;
  if (i4 < 3 * MB) {
    const float* src = (i4 < MB) ? wq : (i4 < 2 * MB ? wk : wv);
    long off = i4 & (MB - 1);
    float4 v = *(const float4*)&src[off];
    ushort4 o; o.x=f2bf(v.x); o.y=f2bf(v.y); o.z=f2bf(v.z); o.w=f2bf(v.w);
    *(ushort4*)&wcat[i4] = o;
  } else if (i4 < 4 * MB) {
    long off = i4 - 3 * MB;
    float4 v = *(const float4*)&ow[off];
    ushort4 o; o.x=f2bf(v.x); o.y=f2bf(v.y); o.z=f2bf(v.z); o.w=f2bf(v.w);
    *(ushort4*)&owb[off] = o;
  } else if (i4 < 5 * MB) {
    long off = i4 - 4 * MB;
    float4 v = *(const float4*)&w[off];
    ushort4 o;
    o.x=f2bf(expf(v.x)); o.y=f2bf(expf(v.y)); o.z=f2bf(expf(v.z)); o.w=f2bf(expf(v.w));
    *(ushort4*)&ewb[off] = o;
  } else {
    long i = i4 - 5 * MB;
    if (i < 3072) {
      const float* src = (i < 1024) ? bq : (i < 2048 ? bk : bv);
      long off = i & 1023;
      *(float4*)&bcat[i] = *(const float4*)&src[off];
    }
  }
}

// E[b,s,j] = exp(k[b,s,j] + w[s,j]) ; k lives in qkv cols [1024,2048)
__global__ void ew_E(const ushort* __restrict__ qkv, const float* __restrict__ w,
                     ushort* __restrict__ E)
{
  long e4 = ((long)blockIdx.x * 256 + threadIdx.x) * 4;
  long m = e4 >> 10;            // b*1024+s
  int  j = (int)(e4 & 1023);
  int  s = (int)(m & 1023);
  ushort4 kv = *(const ushort4*)&qkv[m * 3072 + 1024 + j];
  float4  wv = *(const float4*)&w[(long)s * 1024 + j];
  ushort4 o;
  o.x = f2bf(expf(bf2f(kv.x) + wv.x));
  o.y = f2bf(expf(bf2f(kv.y) + wv.y));
  o.z = f2bf(expf(bf2f(kv.z) + wv.z));
  o.w = f2bf(expf(bf2f(kv.w) + wv.w));
  *(ushort4*)&E[e4] = o;
}

// per-batch transpose of a qkv column segment; optional exp.
// dst[b][d][s] = f(qkv[b*1024+s][colOff+d])
template<bool DOEXP>
__global__ void transpose_seg(const ushort* __restrict__ qkv,
                              ushort* __restrict__ dst, int colOff)
{
  __shared__ float tile[32][33];
  int b  = blockIdx.z;
  int s0 = blockIdx.y * 32, d0 = blockIdx.x * 32;
  int tx = threadIdx.x, ty = threadIdx.y;   // (32,8)
#pragma unroll
  for (int i = 0; i < 4; ++i) {
    int s = s0 + ty + i * 8;
    float f = bf2f(qkv[((long)(b * 1024 + s)) * 3072 + colOff + d0 + tx]);
    if (DOEXP) f = expf(f);
    tile[ty + i * 8][tx] = f;
  }
  __syncthreads();
#pragma unroll
  for (int i = 0; i < 4; ++i) {
    int d = d0 + ty + i * 8;
    dst[((long)b * 1024 + d) * 1024 + s0 + tx] = f2bf(tile[tx][ty + i * 8]);
  }
}

// y = sigmoid(q) * num / den   (q from qkv cols [0,1024))
__global__ void ew_y(const ushort* __restrict__ qkv, const ushort* __restrict__ num,
                     const ushort* __restrict__ den, ushort* __restrict__ y)
{
  long e4 = ((long)blockIdx.x * 256 + threadIdx.x) * 4;
  long m = e4 >> 10;
  int  d = (int)(e4 & 1023);
  ushort4 q4 = *(const ushort4*)&qkv[m * 3072 + d];
  ushort4 n4 = *(const ushort4*)&num[e4];
  ushort4 d4 = *(const ushort4*)&den[e4];
  ushort4 o;
  {
    float q = bf2f(q4.x), s = 1.f / (1.f + expf(-q));
    o.x = f2bf(s * bf2f(n4.x) / bf2f(d4.x));
  }
  {
    float q = bf2f(q4.y), s = 1.f / (1.f + expf(-q));
    o.y = f2bf(s * bf2f(n4.y) / bf2f(d4.y));
  }
  {
    float q = bf2f(q4.z), s = 1.f / (1.f + expf(-q));
    o.z = f2bf(s * bf2f(n4.z) / bf2f(d4.z));
  }
  {
    float q = bf2f(q4.w), s = 1.f / (1.f + expf(-q));
    o.w = f2bf(s * bf2f(n4.w) / bf2f(d4.w));
  }
  *(ushort4*)&y[e4] = o;
}

// ---------------------------------------------------------------------------
extern "C" void kernel_launch(void* const* d_in, const int* in_sizes, int n_in,
                              void* d_out, int out_size, void* d_ws, size_t ws_size,
                              hipStream_t stream)
{
  const float* x     = (const float*)d_in[0];
  const float* wq_w  = (const float*)d_in[1];
  const float* wq_b  = (const float*)d_in[2];
  const float* wk_w  = (const float*)d_in[3];
  const float* wk_b  = (const float*)d_in[4];
  const float* wv_w  = (const float*)d_in[5];
  const float* wv_b  = (const float*)d_in[6];
  const float* w     = (const float*)d_in[7];
  const float* out_w = (const float*)d_in[8];
  const float* out_b = (const float*)d_in[9];
  float* out = (float*)d_out;

  const long MB = 1048576;              // 1M elements
  char* ws = (char*)d_ws;
  size_t o = 0;
  auto alloc = [&](size_t bytes){ size_t r = o; o += (bytes + 255) & ~(size_t)255; return r; };

  ushort* xb   = (ushort*)(ws + alloc(8192 * 1024 * 2));   // x bf16
  ushort* wcat = (ushort*)(ws + alloc(3072 * 1024 * 2));   // [wq|wk|wv] bf16
  ushort* owb  = (ushort*)(ws + alloc(1024 * 1024 * 2));   // out_w bf16
  ushort* ewb  = (ushort*)(ws + alloc(1024 * 1024 * 2));   // exp(w) bf16
  float*  bcat = (float*) (ws + alloc(3072 * 4));          // [bq|bk|bv]
  ushort* qkvb = (ushort*)(ws + alloc(8192 * 3072 * 2));   // q|k|v bf16
  ushort* Eb   = (ushort*)(ws + alloc(8 * MB * 2));        // exp(k+w)
  ushort* vTb  = (ushort*)(ws + alloc(8 * MB * 2));        // v^T per batch
  ushort* EKTb = (ushort*)(ws + alloc(8 * MB * 2));        // exp(k)^T per batch
  ushort* numb = (ushort*)(ws + alloc(8 * MB * 2));
  ushort* denb = (ushort*)(ws + alloc(8 * MB * 2));
  ushort* yb   = (ushort*)(ws + alloc(8 * MB * 2));
  (void)ws_size; (void)in_sizes; (void)n_in; (void)out_size;

  cvt_x<<<8192, 256, 0, stream>>>(x, xb);
  prep<<<5123, 256, 0, stream>>>(wq_w, wk_w, wv_w, out_w, w,
                                 wq_b, wk_b, wv_b, wcat, owb, ewb, bcat);

  // qkv = x @ wcat^T + bcat : M=8192 N=3072 K=1024
  gemm_bt<0><<<dim3(24, 64, 1), 256, 0, stream>>>(
      xb, wcat, qkvb, bcat, 3072, 1024, 0, 0, 0);

  ew_E<<<8192, 256, 0, stream>>>(qkvb, w, Eb);
  transpose_seg<false><<<dim3(32, 32, 8), dim3(32, 8), 0, stream>>>(qkvb, vTb, 2048);
  transpose_seg<true ><<<dim3(32, 32, 8), dim3(32, 8), 0, stream>>>(qkvb, EKTb, 1024);

  // num[b] = E[b] @ v[b]  (B^T = vT) : per batch 1024^3
  gemm_bt<0><<<dim3(8, 8, 8), 256, 0, stream>>>(
      Eb, vTb, numb, nullptr, 1024, 1024, MB, MB, MB);
  // den[b] = exp(w) @ exp(k[b])  (B^T = EKT)
  gemm_bt<0><<<dim3(8, 8, 8), 256, 0, stream>>>(
      ewb, EKTb, denb, nullptr, 1024, 1024, 0, MB, MB);

  ew_y<<<8192, 256, 0, stream>>>(qkvb, numb, denb, yb);

  // out = y @ out_w^T + out_b : M=8192 N=1024 K=1024, fp32 store
  gemm_bt<1><<<dim3(8, 64, 1), 256, 0, stream>>>(
      yb, owb, out, out_b, 1024, 1024, 0, 0, 0);
}